// Round 11
// baseline (4525.345 us; speedup 1.0000x reference)
//
#include <hip/hip_runtime.h>
#include <hip/hip_bf16.h>
#include <cstdint>

// Neural ODE: 10 Heun steps of f(y) = tanh(y@W1 + b1)@W2 + b2
// BATCH=8192, D=512, H=2048, dt=0.1
// R17: SINGLE-LAUNCH fused integrator. Key realization: Heun + row-wise f
// => each batch row integrates independently; block b's eval input is the
// slab block b itself produced. All 20 launches / state round-trips / pack
// round-trips / per-eval prologues were pure overhead.
//   - ONE kernel, grid 256; each block carries its 32 rows through all
//     10 steps. y and p live in REGISTERS (16 fp32 each per lane, C/D
//     layout); eval inputs cross evals as bf16 via direct scatter into yA
//     (same verified formula the R13 epilogue used for outPack).
//   - Eval core is R13 verbatim: CW=512, NCH=4, 32x32x16, one barrier per
//     window, double-buffered hA. Numerics bit-identical to R13.
//   - Weight stream (4MB/CU/eval from L2) unchanged — this removes the
//     ~10-15us/eval-pair of launch + state-HBM + prologue/drain overhead.
// VGPR hook: expect ~96-124, localMem 0 (ys/pp are non-remat; spill would
// show as scratch traffic + FETCH/WRITE inflation).
// Dead axes: reg-batching >128 VGPR (R7/R14), serialized scatter (R8),
// CW512@16x16 (R10), 1-deep prefetch (R11), wave specialization (R12),
// hand-interleave/pinning (R15), CW=1024 (R16 neutral).

#define BATCHN 8192
#define DDIM 512
#define HDIM 2048
#define CW 512          // chunk width over H
#define NCH (HDIM / CW) // 4
#define NEVAL 20        // 10 Heun steps x 2 f-evals

typedef short short8 __attribute__((ext_vector_type(8)));
typedef float floatx16 __attribute__((ext_vector_type(16)));

__device__ __forceinline__ unsigned short f2bf(float f) {
  union { __hip_bfloat16 h; unsigned short u; } cv;
  cv.h = __float2bfloat16(f);
  return cv.u;
}

__device__ __forceinline__ float fast_tanh(float x) {
  float e = __expf(2.0f * x);
  return 1.0f - 2.0f / (e + 1.0f);
}

// 32x32x16 fragment conventions (verified by R13/R16 passing):
//  A-frag: lane holds A[m = lane&31][k = (lane>>5)*8 + j], j=0..7 (16B)
//  B-frag: lane holds B[n = lane&31][k = (lane>>5)*8 + j]   (BT row-major)
//  C/D:    col = lane&31, row = (reg&3) + 8*(reg>>2) + 4*(lane>>5)
// Packed weights: frag f stored at [(f*64 + lane)*8] halves.
//  w1p: f = nb*32 + kb   (nb = H col-tile/32: 0..63,  kb = D k-step: 0..31)
//  w2p: f = nb*128 + kb  (nb = D col-tile/32: 0..15,  kb = H k-step: 0..127)

__global__ __launch_bounds__(1024, 4) void fused_ode(
    const unsigned short* __restrict__ w1p,
    const unsigned short* __restrict__ w2p,
    const float* __restrict__ b1,
    const float* __restrict__ b2,
    const float* __restrict__ y0,
    float* __restrict__ yOut) {
  __shared__ unsigned short yA[32 * 512];       // 32 KB, A32 frags ks=0..31
  __shared__ unsigned short hA[2][32 * 512];    // 2 x 32 KB, A32 frags/chunk

  const int tid  = threadIdx.x;
  const int lane = tid & 63;
  const int w    = tid >> 6;    // wave 0..15
  const int c31  = lane & 31;
  const int lhi  = lane >> 5;   // 0..1
  const int blk  = blockIdx.x;  // 0..255
  const int B0   = blk * 32;    // slab base row

  // Lane's output-column and scatter constants (C/D layout, col = w*32+c31).
  const int ncol = w * 32 + c31;          // 0..511
  const int ksf  = ncol >> 4;             // yA frag index
  const int lh   = (ncol >> 3) & 1;
  const int jj   = ncol & 7;
  const int mhi  = lhi * 4;

  // Per-chunk b1 biases + b2 bias (loop-invariant).
  float bb1v[NCH];
#pragma unroll
  for (int c = 0; c < NCH; ++c) bb1v[c] = b1[c * CW + ncol];
  const float bb2 = b2[ncol];

  // Load initial state y0 into registers (C/D layout) and scatter to yA.
  float ys[16];   // carries y (between steps) / ynew
  float pp[16];   // carries p = y + 0.05*k1 between eval1 and eval2
#pragma unroll
  for (int reg = 0; reg < 16; ++reg) {
    const int mrow = (reg & 3) + 8 * (reg >> 2) + mhi;
    ys[reg] = y0[(size_t)(B0 + mrow) * DDIM + ncol];
  }
#pragma unroll
  for (int reg = 0; reg < 16; ++reg) {
    const int mrow = (reg & 3) + 8 * (reg >> 2) + mhi;
    yA[(ksf * 64 + (mrow + 32 * lh)) * 8 + jj] = f2bf(ys[reg]);
  }
  __syncthreads();

#pragma unroll 1
  for (int e = 0; e < NEVAL; ++e) {
    floatx16 accY = {};  // GEMM2 acc: col = ncol, 16 rows

#pragma unroll
    for (int c = 0; c < NCH; ++c) {
      // ---- phase1: acc1 = yA @ W1[:, (c*16+w)*32 .. +32] ----
      floatx16 acc1 = {};
      const unsigned short* w1b =
          w1p + ((size_t)((c * 16 + w) * 32) * 64 + lane) * 8;
#pragma unroll
      for (int ks = 0; ks < 32; ++ks) {
        short8 a = *(const short8*)&yA[(ks * 64 + lane) * 8];
        short8 b = *(const short8*)(w1b + (size_t)ks * 512);
        acc1 = __builtin_amdgcn_mfma_f32_32x32x16_bf16(a, b, acc1, 0, 0, 0);
      }

      // bias + tanh + scatter into hA[c&1] (A32-frag layout, k = h-col)
      {
        unsigned short* hbuf = hA[c & 1];
        const float bb = bb1v[c];
#pragma unroll
        for (int reg = 0; reg < 16; ++reg) {
          const int m = (reg & 3) + 8 * (reg >> 2) + mhi;   // C/D row
          hbuf[(ksf * 64 + (m + 32 * lh)) * 8 + jj] =
              f2bf(fast_tanh(acc1[reg] + bb));
        }
      }

      // ---- phase2 for chunk c-1: accY += h_prev @ W2-slice ----
      if (c > 0) {
        const int cc = c - 1;
        const unsigned short* hp = hA[cc & 1];
        const unsigned short* w2b =
            w2p + ((size_t)(w * 128 + cc * 32) * 64 + lane) * 8;
#pragma unroll
        for (int ks = 0; ks < 32; ++ks) {
          short8 a = *(const short8*)&hp[(ks * 64 + lane) * 8];
          short8 b = *(const short8*)(w2b + (size_t)ks * 512);
          accY = __builtin_amdgcn_mfma_f32_32x32x16_bf16(a, b, accY, 0, 0, 0);
        }
      }
      __syncthreads();
    }
    // tail phase2: chunk NCH-1 (buffer (NCH-1)&1 = 1)
    {
      const int cc = NCH - 1;
      const unsigned short* hp = hA[cc & 1];
      const unsigned short* w2b =
          w2p + ((size_t)(w * 128 + cc * 32) * 64 + lane) * 8;
#pragma unroll
      for (int ks = 0; ks < 32; ++ks) {
        short8 a = *(const short8*)&hp[(ks * 64 + lane) * 8];
        short8 b = *(const short8*)(w2b + (size_t)ks * 512);
        accY = __builtin_amdgcn_mfma_f32_32x32x16_bf16(a, b, accY, 0, 0, 0);
      }
    }
    // All waves have passed the last in-loop barrier => all yA reads for
    // this eval are done; tail reads hA only. Safe to scatter next input.

    // Epilogue: Heun combine in registers, scatter next eval input to yA.
    if ((e & 1) == 0) {
      // eval1: v = k1. p = y + 0.05*k1 (regs); ymid = y + 0.1*k1 -> yA.
#pragma unroll
      for (int reg = 0; reg < 16; ++reg) {
        const int mrow = (reg & 3) + 8 * (reg >> 2) + mhi;
        const float v = accY[reg] + bb2;
        pp[reg] = ys[reg] + 0.05f * v;
        const float nv = ys[reg] + 0.1f * v;   // ymid
        yA[(ksf * 64 + (mrow + 32 * lh)) * 8 + jj] = f2bf(nv);
      }
    } else {
      // eval2: v = k2. ynew = p + 0.05*k2 -> regs + yA.
#pragma unroll
      for (int reg = 0; reg < 16; ++reg) {
        const int mrow = (reg & 3) + 8 * (reg >> 2) + mhi;
        const float v = accY[reg] + bb2;
        const float yn = pp[reg] + 0.05f * v;
        ys[reg] = yn;
        yA[(ksf * 64 + (mrow + 32 * lh)) * 8 + jj] = f2bf(yn);
      }
    }
    __syncthreads();  // yA(next eval input) visible; hA free for reuse
  }

  // Final store: ys holds y(t=1.0) fp32.
#pragma unroll
  for (int reg = 0; reg < 16; ++reg) {
    const int mrow = (reg & 3) + 8 * (reg >> 2) + mhi;
    yOut[(size_t)(B0 + mrow) * DDIM + ncol] = ys[reg];
  }
}

// Pack weight [K][N] fp32 -> 32x32 B-frag order: frag f = nb*KB + kb,
// lane entry = src[kb*16 + (lane>>5)*8 + j][nb*32 + (lane&31)].
__global__ void pack_b(const float* __restrict__ src, unsigned short* __restrict__ dst,
                       int KB, int N) {
  const int t = blockIdx.x * 256 + threadIdx.x;
  const int lane = t & 63, f = t >> 6;
  const int nb = f / KB, kb = f % KB;
  const int k0 = kb * 16 + (lane >> 5) * 8, n = nb * 32 + (lane & 31);
  short8 v;
#pragma unroll
  for (int j = 0; j < 8; ++j)
    v[j] = (short)f2bf(src[(size_t)(k0 + j) * N + n]);
  *(short8*)&dst[(size_t)t * 8] = v;
}

extern "C" void kernel_launch(void* const* d_in, const int* in_sizes, int n_in,
                              void* d_out, int out_size, void* d_ws, size_t ws_size,
                              hipStream_t stream) {
  const float* y0 = (const float*)d_in[0];
  const float* W1 = (const float*)d_in[1];  // [512][2048]
  const float* b1 = (const float*)d_in[2];  // [2048]
  const float* W2 = (const float*)d_in[3];  // [2048][512]
  const float* b2 = (const float*)d_in[4];  // [512]

  char* ws = (char*)d_ws;
  unsigned short* w1p = (unsigned short*)(ws);                        // 2 MB
  unsigned short* w2p = (unsigned short*)(ws + (size_t)(2u << 20));   // 2 MB

  // Pre-pass: pack weights (2048 frags each).
  pack_b<<<512, 256, 0, stream>>>(W1, w1p, 32, HDIM);
  pack_b<<<512, 256, 0, stream>>>(W2, w2p, 128, DDIM);

  // Single fused integration kernel: 10 Heun steps, rows are independent.
  fused_ode<<<dim3(256), dim3(1024), 0, stream>>>(
      w1p, w2p, b1, b2, y0, (float*)d_out);
}

// Round 13
// 988.871 us; speedup vs baseline: 4.5763x; 4.5763x over previous
//
#include <hip/hip_runtime.h>
#include <hip/hip_bf16.h>
#include <cstdint>

// Neural ODE: 10 Heun steps of f(y) = tanh(y@W1 + b1)@W2 + b2
// BATCH=8192, D=512, H=2048, dt=0.1
// R19 = R13 (56.6us/eval) with GEMM2 converted to INT8:
//  - h = tanh(.) in (-1,1): fixed scale 127, quant err 0.0023 abs ~= bf16's
//    own h error. No dynamic-range machinery.
//  - W2 int8 with per-column scale (qs[n] = colmax/127); scale applied in
//    the EPILOGUE (C/D col is lane-uniform -> 1 mult/reg). rms err 0.009
//    sigma (4x better than fp8's 0.036 sigma; R18's fp8 failed at 0.156 vs
//    threshold 0.126 — int8 predicted ~0.05).
//  - mfma_i32_32x32x32_i8: K=32 -> GEMM2 MFMA halves; i32 accum EXACT;
//    W2 bytes 2->1 MB (weight stream 4->3 MB/CU/eval); hA bf16->int8
//    (LDS -20%); ZERO dequant VALU (the killer of plain int8-to-bf16).
//  - Layout-risk retired: A(hA) and B(w2p8) packed with the SAME assumed
//    (lane,byte)->k bijection => any mismatch vs true HW mapping permutes
//    both sides of the dot product identically (invariant). C/D layout is
//    HW-verified dtype-independent (m121-128, incl i8 32x32).
// GEMM1 / yA staging / barriers: byte-identical to R13.
// Dead axes: schedule edits (R8/11/12/14/15), CW {512@16x16,1024} (R10/16),
// single-launch fusion (R17 L2-thrash), fp8 weights (R18 accuracy).

#define BATCHN 8192
#define DDIM 512
#define HDIM 2048
#define CW 512          // chunk width over H
#define NCH (HDIM / CW) // 4

typedef short short8 __attribute__((ext_vector_type(8)));
typedef float floatx16 __attribute__((ext_vector_type(16)));
typedef int int4v __attribute__((ext_vector_type(4)));
typedef int intx16 __attribute__((ext_vector_type(16)));

__device__ __forceinline__ unsigned short f2bf(float f) {
  union { __hip_bfloat16 h; unsigned short u; } cv;
  cv.h = __float2bfloat16(f);
  return cv.u;
}

__device__ __forceinline__ float fast_tanh(float x) {
  float e = __expf(2.0f * x);
  return 1.0f - 2.0f / (e + 1.0f);
}

// 32x32 fragment conventions (bf16 verified R13; i8 by the same pattern):
//  A-frag: lane holds A[m = lane&31][k-slice (lane>>5)], 8 bf16 / 16 i8
//  B-frag: lane holds B[n = lane&31][k-slice (lane>>5)]   (BT row-major)
//  C/D:    col = lane&31, row = (reg&3) + 8*(reg>>2) + 4*(lane>>5)
// Packed buffers: frag f at [(f*64 + lane)*elem] units.
//  yPack: f = rb*32 + ks   (bf16; rb = row/32: 0..255, ks: 0..31)
//  w1p:   f = nb*32 + kb   (bf16; nb: 0..63, kb: 0..31)
//  w2p8:  f = nb*64 + kb   (int8; nb = D col-tile/32: 0..15, kb: 0..63,
//                           16 B/lane, K=32 per frag)

__global__ __launch_bounds__(1024, 4) void fused_feval(
    const unsigned short* __restrict__ yPack,   // packed bf16 eval input
    const unsigned short* __restrict__ w1p,     // packed bf16 W1
    const signed char* __restrict__ w2p8,       // packed int8 W2
    const float* __restrict__ qsArr,            // per-col W2 scale (max/127)
    const float* __restrict__ b1,
    const float* __restrict__ b2,
    const float* __restrict__ stateIn,   // EPI1: y fp32 ; EPI2: p fp32
    float* __restrict__ stateOut,        // EPI1: p      ; EPI2: ynew
    unsigned short* __restrict__ outPack,// packed bf16 next-eval input
    int epi) {                           // 1 or 2
  __shared__ unsigned short yA[32 * 512];     // 32 KB, bf16 A32 frags
  __shared__ signed char hA8[2][32 * CW];     // 2 x 16 KB, int8 A32 frags

  const int tid  = threadIdx.x;
  const int lane = tid & 63;
  const int w    = tid >> 6;    // wave 0..15
  const int c31  = lane & 31;
  const int lhi  = lane >> 5;   // 0..1
  const int blk  = blockIdx.x;  // 0..255
  const int B0   = blk * 32;    // slab base row

  // phase0: linear copy of this block's 32 KB packed y-slab into LDS.
  {
    const unsigned short* src = yPack + (size_t)blk * (32 * 512);
    __builtin_amdgcn_global_load_lds(
        (const __attribute__((address_space(1))) void*)(uintptr_t)(src + (size_t)tid * 8),
        (__attribute__((address_space(3))) void*)(uint32_t)(uintptr_t)&yA[tid * 8],
        16, 0, 0);
    __builtin_amdgcn_global_load_lds(
        (const __attribute__((address_space(1))) void*)(uintptr_t)(src + (size_t)(1024 + tid) * 8),
        (__attribute__((address_space(3))) void*)(uint32_t)(uintptr_t)&yA[(1024 + tid) * 8],
        16, 0, 0);
  }

  // preload per-chunk b1 biases (lane's GEMM1 col in chunk c = w*32+c31).
  float bb1v[NCH];
#pragma unroll
  for (int c = 0; c < NCH; ++c) bb1v[c] = b1[c * CW + w * 32 + c31];

  __syncthreads();

  intx16 accY = {};  // GEMM2 i32 acc: col = w*32 + c31, 16 rows (EXACT)

#pragma unroll
  for (int c = 0; c < NCH; ++c) {
    // ---- phase1 (bf16, identical to R13): acc1 = y @ W1-slice ----
    floatx16 acc1 = {};
    const unsigned short* w1b =
        w1p + ((size_t)((c * 16 + w) * 32) * 64 + lane) * 8;
#pragma unroll
    for (int ks = 0; ks < 32; ++ks) {
      short8 a = *(const short8*)&yA[(ks * 64 + lane) * 8];
      short8 b = *(const short8*)(w1b + (size_t)ks * 512);
      acc1 = __builtin_amdgcn_mfma_f32_32x32x16_bf16(a, b, acc1, 0, 0, 0);
    }

    // bias + tanh + int8 quant + scatter into hA8[c&1]
    // lane owns h-col kloc = w*32+c31 -> frag ksf=w, k_local=c31;
    // reader lane = (c31>=16?32:0)+m, byte j = c31&15.
    {
      signed char* hbuf = hA8[c & 1];
      const float bb = bb1v[c];
      const int khalf = (c31 >> 4) << 5;   // 0 or 32
      const int jj8 = c31 & 15;
      const int mhi = lhi * 4;
#pragma unroll
      for (int reg = 0; reg < 16; ++reg) {
        const int m = (reg & 3) + 8 * (reg >> 2) + mhi;   // C/D row
        const float hv = fast_tanh(acc1[reg] + bb);       // in (-1,1)
        hbuf[(w * 64 + khalf + m) * 16 + jj8] =
            (signed char)(int)rintf(hv * 127.0f);
      }
    }

    // ---- phase2 for chunk c-1: accY += h8_prev @ W2-slice (i8 MFMA) ----
    if (c > 0) {
      const int cc = c - 1;
      const signed char* hp = hA8[cc & 1];
      const signed char* w2b =
          w2p8 + ((size_t)(w * 64 + cc * 16) * 64 + lane) * 16;
#pragma unroll
      for (int ks = 0; ks < 16; ++ks) {
        int4v a = *(const int4v*)&hp[(ks * 64 + lane) * 16];
        int4v b = *(const int4v*)(w2b + (size_t)ks * 1024);
        accY = __builtin_amdgcn_mfma_i32_32x32x32_i8(a, b, accY, 0, 0, 0);
      }
    }
    __syncthreads();
  }
  // tail phase2: chunk NCH-1 (buffer (NCH-1)&1 = 1)
  {
    const int cc = NCH - 1;
    const signed char* hp = hA8[cc & 1];
    const signed char* w2b =
        w2p8 + ((size_t)(w * 64 + cc * 16) * 64 + lane) * 16;
#pragma unroll
    for (int ks = 0; ks < 16; ++ks) {
      int4v a = *(const int4v*)&hp[(ks * 64 + lane) * 16];
      int4v b = *(const int4v*)(w2b + (size_t)ks * 1024);
      accY = __builtin_amdgcn_mfma_i32_32x32x32_i8(a, b, accY, 0, 0, 0);
    }
  }
  __syncthreads();  // all waves done reading hA8 before reuse as staging

  // Epilogue: descale (qs/127), add b2, Heun combine, pack bf16 result.
  {
    unsigned short* pbuf = (unsigned short*)&hA8[0][0];  // 32 KB staging
    const int ncol = w * 32 + c31;     // 0..511
    const float sc = qsArr[ncol] * (1.0f / 127.0f);
    const float bb = b2[ncol];
    const int ksf = ncol >> 4;
    const int lh  = (ncol >> 3) & 1;
    const int jj  = ncol & 7;
    const int mhi = lhi * 4;
#pragma unroll
    for (int reg = 0; reg < 16; ++reg) {
      const int mrow = (reg & 3) + 8 * (reg >> 2) + mhi;
      const int row = B0 + mrow;
      const size_t idx = (size_t)row * DDIM + ncol;
      const float v = (float)accY[reg] * sc + bb;
      float nv;
      if (epi == 1) {
        const float y = stateIn[idx];
        stateOut[idx] = y + 0.05f * v;   // p = y + (dt/2)*k1
        nv = y + 0.1f * v;               // ymid
      } else {
        const float yn = stateIn[idx] + 0.05f * v;  // ynew = p + (dt/2)*k2
        stateOut[idx] = yn;
        nv = yn;
      }
      pbuf[(ksf * 64 + (mrow + 32 * lh)) * 8 + jj] = f2bf(nv);
    }
    __syncthreads();
    unsigned short* dst = outPack + (size_t)blk * (32 * 512);
#pragma unroll
    for (int p = 0; p < 2; ++p) {
      short8 v = *(const short8*)&pbuf[(size_t)(p * 1024 + tid) * 8];
      *(short8*)&dst[(size_t)(p * 1024 + tid) * 8] = v;
    }
  }
}

// Pack weight [K][N] fp32 -> 32x32 bf16 B-frag order (W1).
__global__ void pack_b(const float* __restrict__ src, unsigned short* __restrict__ dst,
                       int KB, int N) {
  const int t = blockIdx.x * 256 + threadIdx.x;
  const int lane = t & 63, f = t >> 6;
  const int nb = f / KB, kb = f % KB;
  const int k0 = kb * 16 + (lane >> 5) * 8, n = nb * 32 + (lane & 31);
  short8 v;
#pragma unroll
  for (int j = 0; j < 8; ++j)
    v[j] = (short)f2bf(src[(size_t)(k0 + j) * N + n]);
  *(short8*)&dst[(size_t)t * 8] = v;
}

// Zero the W2 column-max table.
__global__ void zero_cm(unsigned* __restrict__ cm) { cm[threadIdx.x] = 0u; }

// Per-column absmax of W2 [2048][512]: block b scans k in [b*16, b*16+16).
__global__ void colmax_w2(const float* __restrict__ w2, unsigned* __restrict__ cm) {
  const int n = threadIdx.x;          // 0..511
  const int k0 = blockIdx.x * 16;     // 128 blocks
  float m = 0.0f;
#pragma unroll
  for (int i = 0; i < 16; ++i) m = fmaxf(m, fabsf(w2[(size_t)(k0 + i) * DDIM + n]));
  atomicMax(&cm[n], __float_as_uint(m));
}

// Pack W2 [2048][512] fp32 -> int8 B-frags (f = nb*64 + kb, 16 B/lane)
// + emit qsArr[n]. lane entry = W2[kb*32 + (lane>>5)*16 + j][nb*32+(lane&31)].
__global__ void pack_w2i8(const float* __restrict__ w2, const unsigned* __restrict__ cm,
                          signed char* __restrict__ dst, float* __restrict__ qsArr) {
  const int t = blockIdx.x * 256 + threadIdx.x;  // 64K threads
  const int lane = t & 63, f = t >> 6;
  const int nb = f >> 6, kb = f & 63;
  const int n = nb * 32 + (lane & 31);
  const int k0 = kb * 32 + (lane >> 5) * 16;
  float qs = __uint_as_float(cm[n]) * (1.0f / 127.0f);
  if (qs <= 0.0f) qs = 1.0f;
  if (kb == 0 && (lane >> 5) == 0) qsArr[n] = qs;
  const float inv = 1.0f / qs;
  union { signed char b[16]; int4v v; } o;
#pragma unroll
  for (int j = 0; j < 16; ++j)
    o.b[j] = (signed char)(int)rintf(w2[(size_t)(k0 + j) * DDIM + n] * inv);
  *(int4v*)&dst[(size_t)t * 16] = o.v;
}

// y0 fp32 [8192][512] -> yF fp32 copy + packed bf16 32x32 A-frags.
__global__ void pack_y(const float* __restrict__ y0, float* __restrict__ yF,
                       unsigned short* __restrict__ ypk) {
  const int t = blockIdx.x * 256 + threadIdx.x;
  const int lane = t & 63, f = t >> 6;
  const int rb = f >> 5, ks = f & 31;
  const int row = rb * 32 + (lane & 31), c0 = ks * 16 + (lane >> 5) * 8;
  short8 v;
#pragma unroll
  for (int j = 0; j < 8; ++j) {
    const float x = y0[(size_t)row * DDIM + c0 + j];
    yF[(size_t)row * DDIM + c0 + j] = x;
    v[j] = (short)f2bf(x);
  }
  *(short8*)&ypk[(size_t)t * 8] = v;
}

extern "C" void kernel_launch(void* const* d_in, const int* in_sizes, int n_in,
                              void* d_out, int out_size, void* d_ws, size_t ws_size,
                              hipStream_t stream) {
  const float* y0 = (const float*)d_in[0];
  const float* W1 = (const float*)d_in[1];  // [512][2048]
  const float* b1 = (const float*)d_in[2];  // [2048]
  const float* W2 = (const float*)d_in[3];  // [2048][512]
  const float* b2 = (const float*)d_in[4];  // [512]

  char* ws = (char*)d_ws;
  float*          yF   = (float*)(ws);                         // 16 MB
  float*          pF   = (float*)(ws + (size_t)(16u << 20));   // 16 MB
  unsigned short* ypk  = (unsigned short*)(ws + (size_t)(32u << 20)); // 8 MB
  unsigned short* ympk = (unsigned short*)(ws + (size_t)(40u << 20)); // 8 MB
  unsigned short* w1p  = (unsigned short*)(ws + (size_t)(48u << 20)); // 2 MB
  signed char*    w2p8 = (signed char*)(ws + (size_t)(50u << 20));    // 1 MB
  float*          qsArr = (float*)(ws + (size_t)(51u << 20));         // 2 KB
  unsigned*       cmU   = (unsigned*)(ws + (size_t)(51u << 20) + 4096);

  // Pre-pass: W1 bf16 frags; W2 colmax -> int8 frags + qs table; y0 frags.
  zero_cm<<<1, 512, 0, stream>>>(cmU);
  colmax_w2<<<128, 512, 0, stream>>>(W2, cmU);
  pack_b<<<512, 256, 0, stream>>>(W1, w1p, 32, HDIM);
  pack_w2i8<<<256, 256, 0, stream>>>(W2, cmU, w2p8, qsArr);
  pack_y<<<2048, 256, 0, stream>>>(y0, yF, ypk);

  const dim3 grid(256), blkd(1024);
  for (int s = 0; s < 10; ++s) {
    // eval1: k1 = f(y); p = y + 0.05*k1; ymid = y + 0.1*k1 (packed)
    fused_feval<<<grid, blkd, 0, stream>>>(ypk, w1p, w2p8, qsArr, b1, b2, yF, pF, ympk, 1);
    // eval2: k2 = f(ymid); ynew = p + 0.05*k2 (fp32 + packed)
    float* yOut = (s == 9) ? (float*)d_out : yF;
    fused_feval<<<grid, blkd, 0, stream>>>(ympk, w1p, w2p8, qsArr, b1, b2, pF, yOut, ypk, 2);
  }
}